// Round 7
// baseline (183.192 us; speedup 1.0000x reference)
//
#include <hip/hip_runtime.h>
#include <hip/hip_bf16.h>

typedef __attribute__((ext_vector_type(8))) int   i32x8;   // 32 B = fp8 MFMA A/B operand (8 VGPRs)
typedef __attribute__((ext_vector_type(4))) int   i32x4;
typedef __attribute__((ext_vector_type(4))) float f32x4;   // MFMA C/D

constexpr int BB = 4096;   // batch B
constexpr int D  = 256;    // feature dim
constexpr int R2 = 8192;   // 2B rows of z
constexpr int NSPLIT = 32; // column splits (256 cols per block)
constexpr int CT = 64;     // columns staged per LDS tile
constexpr int NT = (R2 / NSPLIT) / CT;  // 4 tiles per block
constexpr float SQRT2 = 1.41421356237309515f;
constexpr float E2 = 7.38905609893065f;  // exp(2) == exp(diag sim)

// Async 16B/lane global->LDS DMA. Dest is wave-uniform base + lane*16 (HW-fixed).
__device__ __forceinline__ void async16(const unsigned char* g, unsigned char* l) {
    __builtin_amdgcn_global_load_lds(
        (const __attribute__((address_space(1))) void*)g,
        (__attribute__((address_space(3))) void*)l,
        16, 0, 0);
}

// Unit-scale (E8M0 127 = 2^0) MX-fp8 MFMA, fmt A/B = fp8-e4m3. Verified correct in R5/R6.
#define MFMA8(A, B, C) \
    __builtin_amdgcn_mfma_scale_f32_16x16x128_f8f6f4((A), (B), (C), 0, 0, 0, 127, 0, 127)

// Kernel A: L2-normalize rows, scale by sqrt(2), store fp8-e4m3 z[8192][256];
// pos[k] = 2*cos(xi_k, xj_k) in fp32. One wave per pair k. Also zero-inits out[0].
__global__ __launch_bounds__(256) void norm_kernel(const float* __restrict__ xi,
                                                   const float* __restrict__ xj,
                                                   int* __restrict__ z8,
                                                   float* __restrict__ pos,
                                                   float* __restrict__ out) {
    const int wid = threadIdx.x >> 6, lane = threadIdx.x & 63;
    const int k = blockIdx.x * 4 + wid;
    if (blockIdx.x == 0 && threadIdx.x == 0) out[0] = 0.f;
    const float4* a4 = reinterpret_cast<const float4*>(xi + (size_t)k * D);
    const float4* b4 = reinterpret_cast<const float4*>(xj + (size_t)k * D);
    float4 a = a4[lane], b = b4[lane];
    float ssi = a.x*a.x + a.y*a.y + a.z*a.z + a.w*a.w;
    float ssj = b.x*b.x + b.y*b.y + b.z*b.z + b.w*b.w;
    float dot = a.x*b.x + a.y*b.y + a.z*b.z + a.w*b.w;
#pragma unroll
    for (int off = 32; off; off >>= 1) {
        ssi += __shfl_xor(ssi, off);
        ssj += __shfl_xor(ssj, off);
        dot += __shfl_xor(dot, off);
    }
    const float inv_i = 1.0f / fmaxf(sqrtf(ssi), 1e-12f);
    const float inv_j = 1.0f / fmaxf(sqrtf(ssj), 1e-12f);
    const float si = inv_i * SQRT2, sj = inv_j * SQRT2;
    int pi = __builtin_amdgcn_cvt_pk_fp8_f32(a.x*si, a.y*si, 0, false);
    pi     = __builtin_amdgcn_cvt_pk_fp8_f32(a.z*si, a.w*si, pi, true);
    int pj = __builtin_amdgcn_cvt_pk_fp8_f32(b.x*sj, b.y*sj, 0, false);
    pj     = __builtin_amdgcn_cvt_pk_fp8_f32(b.z*sj, b.w*sj, pj, true);
    z8[(size_t)k * 64 + lane]        = pi;
    z8[(size_t)(k + BB) * 64 + lane] = pj;
    if (lane == 0) pos[k] = dot * inv_i * inv_j * 2.0f;
}

// Kernel B: partial[split][r] = sum over this split's 256 columns c of exp(z_r . z_c).
// MX-fp8 16x16x128 MFMA at 2x bf16 rate. 4 waves x 64 rows = 256 rows/block.
// R5/R6 diagnosis: allocator targeted 4 waves/EU (128 VGPRs) and live-range-split
// ~13 regs through scratch in the hot loop -> 223 MB HBM scratch traffic.
// amdgpu_waves_per_eu(2,2) pins the target at 2 waves/EU -> full 256-reg budget,
// no spills. Everything else identical to the verified R6 kernel.
// LDS: B-tiles (64 cols x 256 B = 16 KB) double-buffered via global_load_lds DMA
// issued one tile ahead; granule g of row r at physical granule g^(r&15)
// (swizzle on the DMA *source* address; conflict-free reads; verified correct).
__global__ __launch_bounds__(256)
__attribute__((amdgpu_waves_per_eu(2, 2)))
void sim_kernel(const unsigned char* __restrict__ z8,
                float* __restrict__ partial) {
    __shared__ unsigned char tb[2][CT * D];   // 2 x 16 KB
    const int tid = threadIdx.x;
    const int wid = tid >> 6, lane = tid & 63;
    const int lrow = lane & 15, quad = lane >> 4;
    const int r0 = blockIdx.x * 256 + wid * 64;       // this wave's 64 rows
    const int cbase = blockIdx.y * (R2 / NSPLIT);

    // DMA source mapping (fixed per thread): round i stages row r = i*16 + (tid>>4);
    // physical granule p = tid&15 (forced) <- logical granule p ^ (r&15).
    const int srow = tid >> 4;
    const unsigned char* gstage = z8 + (size_t)(cbase + srow) * D + ((tid & 15) ^ srow) * 16;

    // Issue tile-0 DMA first so it overlaps the A-fragment global loads.
    async16(gstage + 0*4096, &tb[0][0*4096 + wid*1024]);
    async16(gstage + 1*4096, &tb[0][1*4096 + wid*1024]);
    async16(gstage + 2*4096, &tb[0][2*4096 + wid*1024]);
    async16(gstage + 3*4096, &tb[0][3*4096 + wid*1024]);

    // A fragments: 64 rows x K=256, named (m = row-block, k = K-half).
    // Layout (16x16x128 f8f6f4): row = lane&15, k-bytes = (lane>>4)*32 + linear.
    const unsigned char* abase = z8 + (size_t)(r0 + lrow) * D + quad * 32;
    const i32x8 a0k0 = *reinterpret_cast<const i32x8*>(abase + 0*4096      );
    const i32x8 a0k1 = *reinterpret_cast<const i32x8*>(abase + 0*4096 + 128);
    const i32x8 a1k0 = *reinterpret_cast<const i32x8*>(abase + 1*4096      );
    const i32x8 a1k1 = *reinterpret_cast<const i32x8*>(abase + 1*4096 + 128);
    const i32x8 a2k0 = *reinterpret_cast<const i32x8*>(abase + 2*4096      );
    const i32x8 a2k1 = *reinterpret_cast<const i32x8*>(abase + 2*4096 + 128);
    const i32x8 a3k0 = *reinterpret_cast<const i32x8*>(abase + 3*4096      );
    const i32x8 a3k1 = *reinterpret_cast<const i32x8*>(abase + 3*4096 + 128);

    f32x4 racc0 = {0.f,0.f,0.f,0.f}, racc1 = {0.f,0.f,0.f,0.f};
    f32x4 racc2 = {0.f,0.f,0.f,0.f}, racc3 = {0.f,0.f,0.f,0.f};

    __syncthreads();   // tile-0 DMA + afrag loads drained (vmcnt(0) before barrier)

    for (int ct = 0; ct < NT; ++ct) {
        const unsigned char* tbb = tb[ct & 1];
        if (ct + 1 < NT) {
            const unsigned char* gs = gstage + (size_t)(ct + 1) * (CT * D);
            unsigned char* dn = &tb[(ct + 1) & 1][wid * 1024];
            async16(gs + 0*4096, dn + 0*4096);
            async16(gs + 1*4096, dn + 1*4096);
            async16(gs + 2*4096, dn + 2*4096);
            async16(gs + 3*4096, dn + 3*4096);
        }
#pragma unroll
        for (int n = 0; n < 4; ++n) {
            const unsigned char* rbp = tbb + (n*16 + lrow) * D;
            const int pe0 = (quad*2) ^ lrow;         // k-half 0, even granule
            const int pe1 = (8 + quad*2) ^ lrow;     // k-half 1, even granule
            const i32x4 lo0 = *reinterpret_cast<const i32x4*>(rbp + pe0*16);
            const i32x4 hi0 = *reinterpret_cast<const i32x4*>(rbp + (pe0^1)*16);
            const i32x4 lo1 = *reinterpret_cast<const i32x4*>(rbp + pe1*16);
            const i32x4 hi1 = *reinterpret_cast<const i32x4*>(rbp + (pe1^1)*16);
            const i32x8 b0 = __builtin_shufflevector(lo0, hi0, 0,1,2,3,4,5,6,7);
            const i32x8 b1 = __builtin_shufflevector(lo1, hi1, 0,1,2,3,4,5,6,7);

            f32x4 c0 = {0.f,0.f,0.f,0.f}, c1 = {0.f,0.f,0.f,0.f};
            f32x4 c2 = {0.f,0.f,0.f,0.f}, c3 = {0.f,0.f,0.f,0.f};
            c0 = MFMA8(a0k0, b0, c0);  c0 = MFMA8(a0k1, b1, c0);
            c1 = MFMA8(a1k0, b0, c1);  c1 = MFMA8(a1k1, b1, c1);
            c2 = MFMA8(a2k0, b0, c2);  c2 = MFMA8(a2k1, b1, c2);
            c3 = MFMA8(a3k0, b0, c3);  c3 = MFMA8(a3k1, b1, c3);

            racc0[0] += __expf(c0[0]); racc0[1] += __expf(c0[1]);
            racc0[2] += __expf(c0[2]); racc0[3] += __expf(c0[3]);
            racc1[0] += __expf(c1[0]); racc1[1] += __expf(c1[1]);
            racc1[2] += __expf(c1[2]); racc1[3] += __expf(c1[3]);
            racc2[0] += __expf(c2[0]); racc2[1] += __expf(c2[1]);
            racc2[2] += __expf(c2[2]); racc2[3] += __expf(c2[3]);
            racc3[0] += __expf(c3[0]); racc3[1] += __expf(c3[1]);
            racc3[2] += __expf(c3[2]); racc3[3] += __expf(c3[3]);
        }
        __syncthreads();   // all waves done reading tbb; next tile's DMA drained
    }

    // Row sums: reduce over lane bits 0-3 (the col index); row = quad*4 + j.
#define REDUCE_STORE(RV, M)                                                     \
    {                                                                           \
        _Pragma("unroll")                                                       \
        for (int j = 0; j < 4; ++j) {                                           \
            float v = (RV)[j];                                                  \
            v += __shfl_xor(v, 1);                                              \
            v += __shfl_xor(v, 2);                                              \
            v += __shfl_xor(v, 4);                                              \
            v += __shfl_xor(v, 8);                                              \
            if (lrow == 0)                                                      \
                partial[(size_t)blockIdx.y * R2 + r0 + (M)*16 + quad*4 + j] = v;\
        }                                                                       \
    }
    REDUCE_STORE(racc0, 0)
    REDUCE_STORE(racc1, 1)
    REDUCE_STORE(racc2, 2)
    REDUCE_STORE(racc3, 3)
#undef REDUCE_STORE
}

// Kernel C: loss_r = log(exp(p_r) + S_r - e^2) - p_r ; atomicAdd(out, blocksum/R2).
// 32 blocks x 256 threads (256 rows each); out zero-initialized by norm_kernel.
__global__ __launch_bounds__(256) void reduce_kernel(const float* __restrict__ partial,
                                                     const float* __restrict__ pos,
                                                     float* __restrict__ out) {
    __shared__ float wsum[4];
    const int tid = threadIdx.x;
    const int r = blockIdx.x * 256 + tid;
    float S = 0.f;
#pragma unroll
    for (int s = 0; s < NSPLIT; ++s) S += partial[(size_t)s * R2 + r];
    const float p = pos[r & (BB - 1)];
    float lsum = __logf(__expf(p) + S - E2) - p;
#pragma unroll
    for (int off = 32; off; off >>= 1) lsum += __shfl_xor(lsum, off);
    if ((tid & 63) == 0) wsum[tid >> 6] = lsum;
    __syncthreads();
    if (tid == 0) {
        float t = wsum[0] + wsum[1] + wsum[2] + wsum[3];
        atomicAdd(out, t * (1.0f / (float)R2));
    }
}

extern "C" void kernel_launch(void* const* d_in, const int* in_sizes, int n_in,
                              void* d_out, int out_size, void* d_ws, size_t ws_size,
                              hipStream_t stream) {
    (void)in_sizes; (void)n_in; (void)out_size; (void)ws_size;
    const float* xi = (const float*)d_in[0];
    const float* xj = (const float*)d_in[1];
    float* out = (float*)d_out;

    unsigned char* z8 = (unsigned char*)d_ws;                                  // 8192*256 = 2 MB
    float* partial = (float*)((char*)d_ws + (size_t)R2 * D);                   // 32*8192*4 = 1 MB
    float* pos     = (float*)((char*)d_ws + (size_t)R2 * D + (size_t)NSPLIT*R2*4);  // 16 KB

    norm_kernel<<<BB / 4, 256, 0, stream>>>(xi, xj, (int*)z8, pos, out);
    sim_kernel<<<dim3(R2 / 256, NSPLIT), 256, 0, stream>>>(z8, partial);
    reduce_kernel<<<NSPLIT, 256, 0, stream>>>(partial, pos, out);
}

// Round 8
// 91.383 us; speedup vs baseline: 2.0047x; 2.0047x over previous
//
#include <hip/hip_runtime.h>
#include <hip/hip_bf16.h>

typedef __attribute__((ext_vector_type(8))) int   i32x8;   // 32 B = fp8 MFMA A/B operand (8 VGPRs)
typedef __attribute__((ext_vector_type(4))) int   i32x4;
typedef __attribute__((ext_vector_type(4))) float f32x4;   // MFMA C/D

constexpr int BB = 4096;   // batch B
constexpr int D  = 256;    // feature dim
constexpr int R2 = 8192;   // 2B rows of z
constexpr int NSPLIT = 32; // column splits (256 cols per block)
constexpr int CT = 64;     // columns staged per LDS tile
constexpr int NT = (R2 / NSPLIT) / CT;  // 4 tiles per block
constexpr float SQRT2 = 1.41421356237309515f;
constexpr float E2 = 7.38905609893065f;  // exp(2) == exp(diag sim)

// Async 16B/lane global->LDS DMA. Dest is wave-uniform base + lane*16 (HW-fixed).
__device__ __forceinline__ void async16(const unsigned char* g, unsigned char* l) {
    __builtin_amdgcn_global_load_lds(
        (const __attribute__((address_space(1))) void*)g,
        (__attribute__((address_space(3))) void*)l,
        16, 0, 0);
}

// Unit-scale (E8M0 127 = 2^0) MX-fp8 MFMA, fmt A/B = fp8-e4m3. Verified correct in R5-R7.
#define MFMA8(A, B, C) \
    __builtin_amdgcn_mfma_scale_f32_16x16x128_f8f6f4((A), (B), (C), 0, 0, 0, 127, 0, 127)

// Kernel A: L2-normalize rows, scale by sqrt(2), store fp8-e4m3 z[8192][256];
// pos[k] = 2*cos(xi_k, xj_k) in fp32. One wave per pair k. Also zero-inits out[0].
__global__ __launch_bounds__(256) void norm_kernel(const float* __restrict__ xi,
                                                   const float* __restrict__ xj,
                                                   int* __restrict__ z8,
                                                   float* __restrict__ pos,
                                                   float* __restrict__ out) {
    const int wid = threadIdx.x >> 6, lane = threadIdx.x & 63;
    const int k = blockIdx.x * 4 + wid;
    if (blockIdx.x == 0 && threadIdx.x == 0) out[0] = 0.f;
    const float4* a4 = reinterpret_cast<const float4*>(xi + (size_t)k * D);
    const float4* b4 = reinterpret_cast<const float4*>(xj + (size_t)k * D);
    float4 a = a4[lane], b = b4[lane];
    float ssi = a.x*a.x + a.y*a.y + a.z*a.z + a.w*a.w;
    float ssj = b.x*b.x + b.y*b.y + b.z*b.z + b.w*b.w;
    float dot = a.x*b.x + a.y*b.y + a.z*b.z + a.w*b.w;
#pragma unroll
    for (int off = 32; off; off >>= 1) {
        ssi += __shfl_xor(ssi, off);
        ssj += __shfl_xor(ssj, off);
        dot += __shfl_xor(dot, off);
    }
    const float inv_i = 1.0f / fmaxf(sqrtf(ssi), 1e-12f);
    const float inv_j = 1.0f / fmaxf(sqrtf(ssj), 1e-12f);
    const float si = inv_i * SQRT2, sj = inv_j * SQRT2;
    int pi = __builtin_amdgcn_cvt_pk_fp8_f32(a.x*si, a.y*si, 0, false);
    pi     = __builtin_amdgcn_cvt_pk_fp8_f32(a.z*si, a.w*si, pi, true);
    int pj = __builtin_amdgcn_cvt_pk_fp8_f32(b.x*sj, b.y*sj, 0, false);
    pj     = __builtin_amdgcn_cvt_pk_fp8_f32(b.z*sj, b.w*sj, pj, true);
    z8[(size_t)k * 64 + lane]        = pi;
    z8[(size_t)(k + BB) * 64 + lane] = pj;
    if (lane == 0) pos[k] = dot * inv_i * inv_j * 2.0f;
}

// Kernel B: partial[split][r] = sum over this split's 256 columns c of exp(z_r . z_c).
// MX-fp8 16x16x128 MFMA. m=2: 4 waves x 32 rows = 128 rows/block.
// R5-R7 lesson: this toolchain pins the per-wave register budget at 128 for this
// kernel (4 waves/EU) regardless of launch_bounds/waves_per_eu hints; m=4's ~150-reg
// demand spilled ~850 B/thread to scratch (223 MB HBM writes). m=2 demand ~90 regs
// fits the 128 budget with margin -> no spills, at the cost of 2x LDS reads/MFMA
// (mildly LDS-bound, ~1.2-1.4x over the 7.4 us MFMA floor).
// LDS: B-tiles (64 cols x 256 B = 16 KB) double-buffered via global_load_lds DMA
// issued one tile ahead; granule g of row r at physical granule g^(r&15)
// (swizzle on the DMA *source* address; conflict-free; verified R5-R7).
__global__ __launch_bounds__(256) void sim_kernel(const unsigned char* __restrict__ z8,
                                                  float* __restrict__ partial) {
    __shared__ unsigned char tb[2][CT * D];   // 2 x 16 KB
    const int tid = threadIdx.x;
    const int wid = tid >> 6, lane = tid & 63;
    const int lrow = lane & 15, quad = lane >> 4;
    const int r0 = blockIdx.x * 128 + wid * 32;       // this wave's 32 rows
    const int cbase = blockIdx.y * (R2 / NSPLIT);

    // DMA source mapping (fixed per thread): round i stages row r = i*16 + (tid>>4);
    // physical granule p = tid&15 (forced) <- logical granule p ^ (r&15).
    const int srow = tid >> 4;
    const unsigned char* gstage = z8 + (size_t)(cbase + srow) * D + ((tid & 15) ^ srow) * 16;

    // Issue tile-0 DMA first so it overlaps the A-fragment global loads.
    async16(gstage + 0*4096, &tb[0][0*4096 + wid*1024]);
    async16(gstage + 1*4096, &tb[0][1*4096 + wid*1024]);
    async16(gstage + 2*4096, &tb[0][2*4096 + wid*1024]);
    async16(gstage + 3*4096, &tb[0][3*4096 + wid*1024]);

    // A fragments: 32 rows x K=256, named (m = row-block, k = K-half).
    // Layout (16x16x128 f8f6f4): row = lane&15, k-bytes = (lane>>4)*32 + linear.
    const unsigned char* abase = z8 + (size_t)(r0 + lrow) * D + quad * 32;
    const i32x8 a0k0 = *reinterpret_cast<const i32x8*>(abase + 0*4096      );
    const i32x8 a0k1 = *reinterpret_cast<const i32x8*>(abase + 0*4096 + 128);
    const i32x8 a1k0 = *reinterpret_cast<const i32x8*>(abase + 1*4096      );
    const i32x8 a1k1 = *reinterpret_cast<const i32x8*>(abase + 1*4096 + 128);

    f32x4 racc0 = {0.f,0.f,0.f,0.f}, racc1 = {0.f,0.f,0.f,0.f};

    __syncthreads();   // tile-0 DMA + afrag loads drained (vmcnt(0) before barrier)

    for (int ct = 0; ct < NT; ++ct) {
        const unsigned char* tbb = tb[ct & 1];
        if (ct + 1 < NT) {
            const unsigned char* gs = gstage + (size_t)(ct + 1) * (CT * D);
            unsigned char* dn = &tb[(ct + 1) & 1][wid * 1024];
            async16(gs + 0*4096, dn + 0*4096);
            async16(gs + 1*4096, dn + 1*4096);
            async16(gs + 2*4096, dn + 2*4096);
            async16(gs + 3*4096, dn + 3*4096);
        }
#pragma unroll
        for (int n = 0; n < 4; ++n) {
            const unsigned char* rbp = tbb + (n*16 + lrow) * D;
            const int pe0 = (quad*2) ^ lrow;         // k-half 0, even granule
            const int pe1 = (8 + quad*2) ^ lrow;     // k-half 1, even granule
            const i32x4 lo0 = *reinterpret_cast<const i32x4*>(rbp + pe0*16);
            const i32x4 hi0 = *reinterpret_cast<const i32x4*>(rbp + (pe0^1)*16);
            const i32x4 lo1 = *reinterpret_cast<const i32x4*>(rbp + pe1*16);
            const i32x4 hi1 = *reinterpret_cast<const i32x4*>(rbp + (pe1^1)*16);
            const i32x8 b0 = __builtin_shufflevector(lo0, hi0, 0,1,2,3,4,5,6,7);
            const i32x8 b1 = __builtin_shufflevector(lo1, hi1, 0,1,2,3,4,5,6,7);

            f32x4 c0 = {0.f,0.f,0.f,0.f}, c1 = {0.f,0.f,0.f,0.f};
            c0 = MFMA8(a0k0, b0, c0);  c0 = MFMA8(a0k1, b1, c0);
            c1 = MFMA8(a1k0, b0, c1);  c1 = MFMA8(a1k1, b1, c1);

            racc0[0] += __expf(c0[0]); racc0[1] += __expf(c0[1]);
            racc0[2] += __expf(c0[2]); racc0[3] += __expf(c0[3]);
            racc1[0] += __expf(c1[0]); racc1[1] += __expf(c1[1]);
            racc1[2] += __expf(c1[2]); racc1[3] += __expf(c1[3]);
        }
        __syncthreads();   // all waves done reading tbb; next tile's DMA drained
    }

    // Row sums: reduce over lane bits 0-3 (the col index); row = quad*4 + j.
#define REDUCE_STORE(RV, M)                                                     \
    {                                                                           \
        _Pragma("unroll")                                                       \
        for (int j = 0; j < 4; ++j) {                                           \
            float v = (RV)[j];                                                  \
            v += __shfl_xor(v, 1);                                              \
            v += __shfl_xor(v, 2);                                              \
            v += __shfl_xor(v, 4);                                              \
            v += __shfl_xor(v, 8);                                              \
            if (lrow == 0)                                                      \
                partial[(size_t)blockIdx.y * R2 + r0 + (M)*16 + quad*4 + j] = v;\
        }                                                                       \
    }
    REDUCE_STORE(racc0, 0)
    REDUCE_STORE(racc1, 1)
#undef REDUCE_STORE
}

// Kernel C: loss_r = log(exp(p_r) + S_r - e^2) - p_r ; atomicAdd(out, blocksum/R2).
// 32 blocks x 256 threads (256 rows each); out zero-initialized by norm_kernel.
__global__ __launch_bounds__(256) void reduce_kernel(const float* __restrict__ partial,
                                                     const float* __restrict__ pos,
                                                     float* __restrict__ out) {
    __shared__ float wsum[4];
    const int tid = threadIdx.x;
    const int r = blockIdx.x * 256 + tid;
    float S = 0.f;
#pragma unroll
    for (int s = 0; s < NSPLIT; ++s) S += partial[(size_t)s * R2 + r];
    const float p = pos[r & (BB - 1)];
    float lsum = __logf(__expf(p) + S - E2) - p;
#pragma unroll
    for (int off = 32; off; off >>= 1) lsum += __shfl_xor(lsum, off);
    if ((tid & 63) == 0) wsum[tid >> 6] = lsum;
    __syncthreads();
    if (tid == 0) {
        float t = wsum[0] + wsum[1] + wsum[2] + wsum[3];
        atomicAdd(out, t * (1.0f / (float)R2));
    }
}

extern "C" void kernel_launch(void* const* d_in, const int* in_sizes, int n_in,
                              void* d_out, int out_size, void* d_ws, size_t ws_size,
                              hipStream_t stream) {
    (void)in_sizes; (void)n_in; (void)out_size; (void)ws_size;
    const float* xi = (const float*)d_in[0];
    const float* xj = (const float*)d_in[1];
    float* out = (float*)d_out;

    unsigned char* z8 = (unsigned char*)d_ws;                                  // 8192*256 = 2 MB
    float* partial = (float*)((char*)d_ws + (size_t)R2 * D);                   // 32*8192*4 = 1 MB
    float* pos     = (float*)((char*)d_ws + (size_t)R2 * D + (size_t)NSPLIT*R2*4);  // 16 KB

    norm_kernel<<<BB / 4, 256, 0, stream>>>(xi, xj, (int*)z8, pos, out);
    sim_kernel<<<dim3(R2 / 128, NSPLIT), 256, 0, stream>>>(z8, partial);
    reduce_kernel<<<NSPLIT, 256, 0, stream>>>(partial, pos, out);
}